// Round 2
// baseline (422.289 us; speedup 1.0000x reference)
//
#include <hip/hip_runtime.h>
#include <hip/hip_bf16.h>

typedef short bh8 __attribute__((ext_vector_type(8)));      // 8 bf16 (4 VGPR) MFMA frag
typedef float f32x4 __attribute__((ext_vector_type(4)));
typedef float f32x16 __attribute__((ext_vector_type(16)));
typedef unsigned int uint4v __attribute__((ext_vector_type(4)));

__device__ inline bh8 pack8(const float4& a, const float4& b) {
    union { bh8 v; __hip_bfloat16 h[8]; } u;
    u.h[0] = __float2bfloat16(a.x); u.h[1] = __float2bfloat16(a.y);
    u.h[2] = __float2bfloat16(a.z); u.h[3] = __float2bfloat16(a.w);
    u.h[4] = __float2bfloat16(b.x); u.h[5] = __float2bfloat16(b.y);
    u.h[6] = __float2bfloat16(b.z); u.h[7] = __float2bfloat16(b.w);
    return u.v;
}

// ---------------------------------------------------------------------------
// GEMM: C[M,N] = A[M,K] @ W[N,K]^T + bias (torch Linear). A: f32 or bf16,
// W/bias: f32, C: f32 or bf16. bf16 MFMA, f32 acc. 128x128 tile, BK=64,
// 4 waves, mfma_f32_16x16x32_bf16, m97-linear LDS, reg-staged with f32->bf16
// conversion in the staging path.
// ---------------------------------------------------------------------------
template <typename TA, typename TC>
__global__ __launch_bounds__(256) void gemm_bt(
    const TA* __restrict__ A, const float* __restrict__ W,
    const float* __restrict__ bias, TC* __restrict__ C,
    int M, int N, int Ksz)
{
    __shared__ __hip_bfloat16 As[128 * 64];
    __shared__ __hip_bfloat16 Bs[128 * 64];
    const int tid = threadIdx.x;
    const int l = tid & 63, w = tid >> 6;
    const int g4 = l >> 4, rl = l & 15;
    const int nb = N >> 7;
    const int bm = blockIdx.x / nb, bn = blockIdx.x % nb;
    const long m0 = (long)bm * 128, n0 = (long)bn * 128;

    const TA*    ag[4];
    const float* wg[4];
    int lo[4];
#pragma unroll
    for (int i = 0; i < 4; ++i) {
        int c = i * 256 + tid;           // chunk 0..1023
        int row = c >> 3, c8 = c & 7;
        ag[i] = A + (m0 + row) * Ksz + c8 * 8;
        wg[i] = W + (n0 + row) * Ksz + c8 * 8;
        lo[i] = row * 64 + c8 * 8;       // linear LDS element offset
    }

    const int wr = w >> 1, wc = w & 1;
    f32x4 acc[4][4];
#pragma unroll
    for (int i = 0; i < 4; ++i)
#pragma unroll
        for (int j = 0; j < 4; ++j) acc[i][j] = f32x4{0.f, 0.f, 0.f, 0.f};

    const int nk = Ksz >> 6;
    for (int t = 0; t < nk; ++t) {
        bh8 av[4], wv[4];
#pragma unroll
        for (int i = 0; i < 4; ++i) {
            if constexpr (__is_same(TA, float)) {
                float4 x0 = *(const float4*)(ag[i]);
                float4 x1 = *(const float4*)(ag[i] + 4);
                av[i] = pack8(x0, x1);
            } else {
                av[i] = *(const bh8*)(ag[i]);
            }
            float4 y0 = *(const float4*)(wg[i]);
            float4 y1 = *(const float4*)(wg[i] + 4);
            wv[i] = pack8(y0, y1);
            ag[i] += 64; wg[i] += 64;
        }
        __syncthreads();   // previous tile's LDS reads complete
#pragma unroll
        for (int i = 0; i < 4; ++i) {
            *(bh8*)(As + lo[i]) = av[i];
            *(bh8*)(Bs + lo[i]) = wv[i];
        }
        __syncthreads();   // tile staged
#pragma unroll
        for (int kc = 0; kc < 2; ++kc) {
            bh8 af[4], bf[4];
#pragma unroll
            for (int mt = 0; mt < 4; ++mt) {
                int row = wr * 64 + mt * 16 + rl;
                af[mt] = *(const bh8*)(As + row * 64 + 8 * g4 + 32 * kc);
            }
#pragma unroll
            for (int nt = 0; nt < 4; ++nt) {
                int row = wc * 64 + nt * 16 + rl;
                bf[nt] = *(const bh8*)(Bs + row * 64 + 8 * g4 + 32 * kc);
            }
#pragma unroll
            for (int mt = 0; mt < 4; ++mt)
#pragma unroll
                for (int nt = 0; nt < 4; ++nt)
                    acc[mt][nt] = __builtin_amdgcn_mfma_f32_16x16x32_bf16(af[mt], bf[nt], acc[mt][nt], 0, 0, 0);
        }
    }

    // epilogue: + bias (f32). C/D: col=lane&15, row=(lane>>4)*4+reg
    float bv[4];
#pragma unroll
    for (int nt = 0; nt < 4; ++nt)
        bv[nt] = bias[n0 + wc * 64 + nt * 16 + rl];
#pragma unroll
    for (int mt = 0; mt < 4; ++mt) {
#pragma unroll
        for (int r = 0; r < 4; ++r) {
            long row = m0 + wr * 64 + mt * 16 + g4 * 4 + r;
            TC* cp = C + row * N + n0 + wc * 64 + rl;
#pragma unroll
            for (int nt = 0; nt < 4; ++nt) {
                float x = acc[mt][nt][r] + bv[nt];
                if constexpr (__is_same(TC, float)) cp[nt * 16] = x;
                else cp[nt * 16] = __float2bfloat16(x);
            }
        }
    }
}

// ---------------------------------------------------------------------------
// Flash attention, B=4 H=16 S=2048 D=64, inputs [B*S, E] bf16 (from ws).
// 8 waves x 32 q-rows (QB=256), KVBLK=64, mfma_f32_32x32x16_bf16.
// Swapped QK^T (S^T = mfma(K,Q)): lane owns one q-row -> in-register softmax.
// PV swapped: O^T = mfma(V^T, P^T); P^T frags via cvt_pk_bf16 + permlane32_swap.
// Mask as additive -1e30 bias (LDS), log2-domain softmax, l==0 -> O=0.
// ---------------------------------------------------------------------------
#define CSC 0.18033688011112042f   /* 0.125 * log2(e) */

__global__ __launch_bounds__(512) void attn_kernel(
    const __hip_bfloat16* __restrict__ Qm, const __hip_bfloat16* __restrict__ Km,
    const __hip_bfloat16* __restrict__ Vm, const int* __restrict__ mask,
    __hip_bfloat16* __restrict__ Om)
{
    __shared__ __hip_bfloat16 Vt[64 * 64];   // V^T tile, XOR-swizzled
    __shared__ float biasS[2048];            // mask bias for this batch
    const int tid = threadIdx.x;
    const int w = tid >> 6, l = tid & 63;
    const int G = l >> 5, c = l & 31;
    const int qb = blockIdx.x & 7;
    const int bh = blockIdx.x >> 3;
    const int b = bh >> 4, h = bh & 15;
    const int q0 = qb * 256 + w * 32;

#pragma unroll
    for (int i = 0; i < 4; ++i) {
        int idx = tid + i * 512;
        biasS[idx] = (mask[b * 2048 + idx] != 0) ? 0.f : -1e30f;
    }

    // Q B-frags: col j = q = c, k = 8G+jj (+16*kc)
    const __hip_bfloat16* qp = Qm + (size_t)(b * 2048 + q0 + c) * 1024 + h * 64 + 8 * G;
    bh8 qf[4];
#pragma unroll
    for (int kc = 0; kc < 4; ++kc) qf[kc] = *(const bh8*)(qp + 16 * kc);

    const __hip_bfloat16* kp0 = Km + (size_t)(b * 2048 + c) * 1024 + h * 64 + 8 * G;
    const __hip_bfloat16* kp1 = kp0 + (size_t)32 * 1024;
    const __hip_bfloat16* vp  = Vm + (size_t)(b * 2048 + (tid >> 3)) * 1024 + h * 64 + (tid & 7) * 8;
    const int vrow = tid >> 3, vd0 = (tid & 7) * 8;

    f32x16 o0 = {0.f}, o1 = {0.f};
    float m_run = -1e29f, l_run = 0.f;

    for (int t = 0; t < 32; ++t) {
        __syncthreads();                       // prev tile's Vt reads done
        {   // stage V^T (transposed, swizzle: kv-chunk bits ^= d&7)
            bh8 vv = *(const bh8*)vp;
#pragma unroll
            for (int j = 0; j < 8; ++j) {
                int d = vd0 + j;
                Vt[(d * 64 + vrow) ^ (j << 3)] = ((const __hip_bfloat16*)&vv)[j];
            }
        }
        // K A-frags direct from global (L2-hot): row = kv0+32ct+c, k = 8G+jj+16kc
        bh8 kf0[4], kf1[4];
#pragma unroll
        for (int kc = 0; kc < 4; ++kc) {
            kf0[kc] = *(const bh8*)(kp0 + 16 * kc);
            kf1[kc] = *(const bh8*)(kp1 + 16 * kc);
        }
        kp0 += (size_t)64 * 1024; kp1 += (size_t)64 * 1024; vp += (size_t)64 * 1024;
        __syncthreads();                       // Vt ready

        // S^T tiles: D[i=kcol][j=q]
        f32x16 s0 = {0.f}, s1 = {0.f};
#pragma unroll
        for (int kc = 0; kc < 4; ++kc) {
            s0 = __builtin_amdgcn_mfma_f32_32x32x16_bf16(kf0[kc], qf[kc], s0, 0, 0, 0);
            s1 = __builtin_amdgcn_mfma_f32_32x32x16_bf16(kf1[kc], qf[kc], s1, 0, 0, 0);
        }

        // scale(log2 domain) + mask bias + row max (lane owns q=c; pair via xor32)
        float mx = -1e30f;
#pragma unroll
        for (int ct = 0; ct < 2; ++ct) {
#pragma unroll
            for (int rb = 0; rb < 4; ++rb) {
                f32x4 bb = *(const f32x4*)&biasS[t * 64 + ct * 32 + rb * 8 + 4 * G];
#pragma unroll
                for (int j = 0; j < 4; ++j) {
                    float sv = (ct ? s1[rb * 4 + j] : s0[rb * 4 + j]) * CSC + bb[j];
                    if (ct) s1[rb * 4 + j] = sv; else s0[rb * 4 + j] = sv;
                    mx = fmaxf(mx, sv);
                }
            }
        }
        mx = fmaxf(mx, __shfl_xor(mx, 32));
        const float m_new = fmaxf(m_run, mx);
        const float fac = __builtin_amdgcn_exp2f(m_run - m_new);
        float ls = 0.f;
#pragma unroll
        for (int i = 0; i < 16; ++i) {
            float p0 = __builtin_amdgcn_exp2f(s0[i] - m_new);
            float p1 = __builtin_amdgcn_exp2f(s1[i] - m_new);
            s0[i] = p0; s1[i] = p1; ls += p0 + p1;
        }
        ls += __shfl_xor(ls, 32);
        l_run = l_run * fac + ls;
        m_run = m_new;
#pragma unroll
        for (int i = 0; i < 16; ++i) { o0[i] *= fac; o1[i] *= fac; }

        // PV: O^T += mfma(V^T-frag, P^T-frag). P^T frag built in-register.
#pragma unroll
        for (int kc2 = 0; kc2 < 4; ++kc2) {
            const f32x16& ps = (kc2 < 2) ? s0 : s1;
            const int R0 = 8 * (kc2 & 1);
            unsigned a0, a1, b0, b1;
            asm("v_cvt_pk_bf16_f32 %0, %1, %2" : "=v"(a0) : "v"(ps[R0 + 0]), "v"(ps[R0 + 1]));
            asm("v_cvt_pk_bf16_f32 %0, %1, %2" : "=v"(a1) : "v"(ps[R0 + 2]), "v"(ps[R0 + 3]));
            asm("v_cvt_pk_bf16_f32 %0, %1, %2" : "=v"(b0) : "v"(ps[R0 + 4]), "v"(ps[R0 + 5]));
            asm("v_cvt_pk_bf16_f32 %0, %1, %2" : "=v"(b1) : "v"(ps[R0 + 6]), "v"(ps[R0 + 7]));
            asm("v_permlane32_swap_b32 %0, %1" : "+v"(a0), "+v"(b0));
            asm("v_permlane32_swap_b32 %0, %1" : "+v"(a1), "+v"(b1));
            uint4v pu = {a0, a1, b0, b1};
            bh8 pf = __builtin_bit_cast(bh8, pu);
            int e0 = (c * 64 + 16 * kc2 + 8 * G) ^ ((c & 7) << 3);
            int e1 = ((c + 32) * 64 + 16 * kc2 + 8 * G) ^ ((c & 7) << 3);
            bh8 vf0 = *(const bh8*)(Vt + e0);
            bh8 vf1 = *(const bh8*)(Vt + e1);
            o0 = __builtin_amdgcn_mfma_f32_32x32x16_bf16(vf0, pf, o0, 0, 0, 0);
            o1 = __builtin_amdgcn_mfma_f32_32x32x16_bf16(vf1, pf, o1, 0, 0, 0);
        }
    }

    // epilogue: O = acc/l (l==0 -> 0), write [B*S, E] bf16, packed stores
    float inv = (l_run > 0.f) ? 1.f / l_run : 0.f;
    __hip_bfloat16* op = Om + (size_t)(b * 2048 + q0 + c) * 1024 + h * 64 + 4 * G;
#pragma unroll
    for (int dt = 0; dt < 2; ++dt) {
#pragma unroll
        for (int rb = 0; rb < 4; ++rb) {
            union { ushort4 u; __hip_bfloat16 hv[4]; } cv;
#pragma unroll
            for (int j = 0; j < 4; ++j) {
                float x = (dt ? o1[rb * 4 + j] : o0[rb * 4 + j]) * inv;
                cv.hv[j] = __float2bfloat16(x);
            }
            *(ushort4*)(op + dt * 32 + rb * 8) = cv.u;
        }
    }
}

// ---------------------------------------------------------------------------
extern "C" void kernel_launch(void* const* d_in, const int* in_sizes, int n_in,
                              void* d_out, int out_size, void* d_ws, size_t ws_size,
                              hipStream_t stream) {
    const float* q  = (const float*)d_in[0];
    const float* k  = (const float*)d_in[1];
    const float* v  = (const float*)d_in[2];
    const int*   mk = (const int*)d_in[3];
    const float* Wq = (const float*)d_in[4];
    const float* bq = (const float*)d_in[5];
    const float* Wk = (const float*)d_in[6];
    const float* bk = (const float*)d_in[7];
    const float* Wv = (const float*)d_in[8];
    const float* bv = (const float*)d_in[9];
    const float* Wo = (const float*)d_in[10];
    const float* bo = (const float*)d_in[11];
    float* out = (float*)d_out;

    const size_t MN = (size_t)8192 * 1024;
    __hip_bfloat16* Qw = (__hip_bfloat16*)d_ws;
    __hip_bfloat16* Kw = Qw + MN;
    __hip_bfloat16* Vw = Kw + MN;
    __hip_bfloat16* Ow = Vw + MN;

    gemm_bt<float, __hip_bfloat16><<<512, 256, 0, stream>>>(q, Wq, bq, Qw, 8192, 1024, 1024);
    gemm_bt<float, __hip_bfloat16><<<512, 256, 0, stream>>>(k, Wk, bk, Kw, 8192, 1024, 1024);
    gemm_bt<float, __hip_bfloat16><<<512, 256, 0, stream>>>(v, Wv, bv, Vw, 8192, 1024, 1024);
    attn_kernel<<<512, 512, 0, stream>>>(Qw, Kw, Vw, mk, Ow);
    gemm_bt<__hip_bfloat16, float><<<512, 256, 0, stream>>>(Ow, Wo, bo, out, 8192, 1024, 1024);
}

// Round 3
// 416.172 us; speedup vs baseline: 1.0147x; 1.0147x over previous
//
#include <hip/hip_runtime.h>
#include <hip/hip_bf16.h>

typedef short bh8 __attribute__((ext_vector_type(8)));      // 8 bf16 (4 VGPR) MFMA frag
typedef float f32x4 __attribute__((ext_vector_type(4)));
typedef float f32x16 __attribute__((ext_vector_type(16)));
typedef unsigned int uint4v __attribute__((ext_vector_type(4)));

#define GLOBAL_P(p) ((const __attribute__((address_space(1))) void*)(p))
#define LDS_P(p)    ((__attribute__((address_space(3))) void*)(p))

__device__ inline bh8 pack8(const float4& a, const float4& b) {
    union { bh8 v; __hip_bfloat16 h[8]; } u;
    u.h[0] = __float2bfloat16(a.x); u.h[1] = __float2bfloat16(a.y);
    u.h[2] = __float2bfloat16(a.z); u.h[3] = __float2bfloat16(a.w);
    u.h[4] = __float2bfloat16(b.x); u.h[5] = __float2bfloat16(b.y);
    u.h[6] = __float2bfloat16(b.z); u.h[7] = __float2bfloat16(b.w);
    return u.v;
}

// ---------------------------------------------------------------------------
// cvt3: f32 -> bf16 for q,k,v (equal sizes). 8 elems/thread/tensor.
// ---------------------------------------------------------------------------
__global__ __launch_bounds__(256) void cvt3(
    const float* __restrict__ a, const float* __restrict__ b, const float* __restrict__ c,
    __hip_bfloat16* __restrict__ oa, __hip_bfloat16* __restrict__ ob, __hip_bfloat16* __restrict__ oc)
{
    size_t i = ((size_t)blockIdx.x * 256 + threadIdx.x) * 8;
    float4 x0 = *(const float4*)(a + i), x1 = *(const float4*)(a + i + 4);
    *(bh8*)(oa + i) = pack8(x0, x1);
    float4 y0 = *(const float4*)(b + i), y1 = *(const float4*)(b + i + 4);
    *(bh8*)(ob + i) = pack8(y0, y1);
    float4 z0 = *(const float4*)(c + i), z1 = *(const float4*)(c + i + 4);
    *(bh8*)(oc + i) = pack8(z0, z1);
}

// ---------------------------------------------------------------------------
// GEMM: C[M,N] = A[M,K] @ W[N,K]^T + bias (torch Linear). A: bf16 (glds-staged,
// m97 linear LDS), W: f32 (reg-staged pack), bias f32, C: f32 or bf16.
// 128x128 tile, BK=64, 4 waves, mfma_f32_16x16x32_bf16.
// ---------------------------------------------------------------------------
template <typename TC>
__global__ __launch_bounds__(256) void gemm_bt(
    const __hip_bfloat16* __restrict__ A, const float* __restrict__ W,
    const float* __restrict__ bias, TC* __restrict__ C,
    int M, int N, int Ksz)
{
    __shared__ __hip_bfloat16 As[128 * 64];
    __shared__ __hip_bfloat16 Bs[128 * 64];
    const int tid = threadIdx.x;
    const int l = tid & 63, w = tid >> 6;
    const int g4 = l >> 4, rl = l & 15;
    const int nb = N >> 7;
    const int bm = blockIdx.x / nb, bn = blockIdx.x % nb;
    const long m0 = (long)bm * 128, n0 = (long)bn * 128;

    const __hip_bfloat16* ag[4];
    const float* wg[4];
    int lo[4], ldsbase[4];
#pragma unroll
    for (int i = 0; i < 4; ++i) {
        int c = i * 256 + tid;           // chunk 0..1023
        int row = c >> 3, c8 = c & 7;
        ag[i] = A + (m0 + row) * Ksz + c8 * 8;
        wg[i] = W + (n0 + row) * Ksz + c8 * 8;
        lo[i] = row * 64 + c8 * 8;       // per-thread linear LDS elem offset (W writes)
        ldsbase[i] = (i * 256 + w * 64) * 8;  // wave-uniform glds base (A)
    }

    const int wr = w >> 1, wc = w & 1;
    f32x4 acc[4][4];
#pragma unroll
    for (int i = 0; i < 4; ++i)
#pragma unroll
        for (int j = 0; j < 4; ++j) acc[i][j] = f32x4{0.f, 0.f, 0.f, 0.f};

    const int nk = Ksz >> 6;
    for (int t = 0; t < nk; ++t) {
        float4 y0[4], y1[4];
#pragma unroll
        for (int i = 0; i < 4; ++i) {    // issue W loads (drain at barrier)
            y0[i] = *(const float4*)(wg[i]);
            y1[i] = *(const float4*)(wg[i] + 4);
            wg[i] += 64;
        }
        __syncthreads();   // previous tile's LDS reads complete
#pragma unroll
        for (int i = 0; i < 4; ++i) {
            __builtin_amdgcn_global_load_lds(GLOBAL_P(ag[i]), LDS_P((__hip_bfloat16*)As + ldsbase[i]), 16, 0, 0);
            ag[i] += 64;
        }
#pragma unroll
        for (int i = 0; i < 4; ++i)
            *(bh8*)(Bs + lo[i]) = pack8(y0[i], y1[i]);
        __syncthreads();   // staged (barrier drains vmcnt+lgkm)
#pragma unroll
        for (int kc = 0; kc < 2; ++kc) {
            bh8 af[4], bf[4];
#pragma unroll
            for (int mt = 0; mt < 4; ++mt) {
                int row = wr * 64 + mt * 16 + rl;
                af[mt] = *(const bh8*)(As + row * 64 + 8 * g4 + 32 * kc);
            }
#pragma unroll
            for (int nt = 0; nt < 4; ++nt) {
                int row = wc * 64 + nt * 16 + rl;
                bf[nt] = *(const bh8*)(Bs + row * 64 + 8 * g4 + 32 * kc);
            }
#pragma unroll
            for (int mt = 0; mt < 4; ++mt)
#pragma unroll
                for (int nt = 0; nt < 4; ++nt)
                    acc[mt][nt] = __builtin_amdgcn_mfma_f32_16x16x32_bf16(af[mt], bf[nt], acc[mt][nt], 0, 0, 0);
        }
    }

    // epilogue: + bias (f32). C/D: col=lane&15, row=(lane>>4)*4+reg
    float bv[4];
#pragma unroll
    for (int nt = 0; nt < 4; ++nt)
        bv[nt] = bias[n0 + wc * 64 + nt * 16 + rl];
#pragma unroll
    for (int mt = 0; mt < 4; ++mt) {
#pragma unroll
        for (int r = 0; r < 4; ++r) {
            long row = m0 + wr * 64 + mt * 16 + g4 * 4 + r;
            TC* cp = C + row * N + n0 + wc * 64 + rl;
#pragma unroll
            for (int nt = 0; nt < 4; ++nt) {
                float x = acc[mt][nt][r] + bv[nt];
                if constexpr (__is_same(TC, float)) cp[nt * 16] = x;
                else cp[nt * 16] = __float2bfloat16(x);
            }
        }
    }
}

// ---------------------------------------------------------------------------
// Flash attention, B=4 H=16 S=2048 D=64, inputs [B*S, E] bf16 (from ws).
// 4 waves x 32 q-rows (QB=128), KVBLK=64, mfma_f32_32x32x16_bf16, grid 1024.
// Swapped QK^T (lane owns q-row -> in-register softmax, log2 domain).
// Pipelined: K[t+1]/V[t+1] global loads issued after QK^T(t); V LDS tile
// double-buffered, transpose-staged with 2-way-conflict write swizzle
// ((d&7)^(d>>3))<<3. Defer-max (T13). XCD-swizzled blockIdx: one (b,h) per XCD.
// ---------------------------------------------------------------------------
#define CSC 0.18033688011112042f   /* 0.125 * log2(e) */
#define THRL 11.0f                 /* defer-max threshold, log2 units */

__global__ __launch_bounds__(256, 3) void attn_kernel(
    const __hip_bfloat16* __restrict__ Qm, const __hip_bfloat16* __restrict__ Km,
    const __hip_bfloat16* __restrict__ Vm, const int* __restrict__ mask,
    __hip_bfloat16* __restrict__ Om)
{
    __shared__ __hip_bfloat16 Vt[2][64 * 64];   // V^T double buffer, swizzled
    __shared__ float biasS[2048];               // mask bias for this batch
    const int tid = threadIdx.x;
    const int w = tid >> 6, l = tid & 63;
    const int G = l >> 5, c = l & 31;
    // XCD swizzle: xcd = id&7 owns bh = xcd*8 + (slot>>4); qb = slot&15
    const int id = blockIdx.x;
    const int xcd = id & 7, slot = id >> 3;
    const int bh = xcd * 8 + (slot >> 4);
    const int qb = slot & 15;
    const int b = bh >> 4, h = bh & 15;
    const int q0 = qb * 128 + w * 32;

#pragma unroll
    for (int i = 0; i < 8; ++i) {
        int idx = i * 256 + tid;
        biasS[idx] = (mask[b * 2048 + idx] != 0) ? 0.f : -1e30f;
    }

    // Q B-frags: col j = q = c, k = 8G+jj (+16*kc)
    const __hip_bfloat16* qp = Qm + (size_t)(b * 2048 + q0 + c) * 1024 + h * 64 + 8 * G;
    bh8 qf[4];
#pragma unroll
    for (int kc = 0; kc < 4; ++kc) qf[kc] = *(const bh8*)(qp + 16 * kc);

    const __hip_bfloat16* kp0 = Km + (size_t)(b * 2048 + c) * 1024 + h * 64 + 8 * G;
    const __hip_bfloat16* kp1 = kp0 + (size_t)32 * 1024;
    const int vr = tid >> 3, vd0 = (tid & 7) * 8;
    const __hip_bfloat16* vp0 = Vm + (size_t)(b * 2048 + vr) * 1024 + h * 64 + vd0;
    const __hip_bfloat16* vp1 = vp0 + (size_t)32 * 1024;

    // prologue: load tile 0
    bh8 kf0[4], kf1[4], vv0, vv1;
#pragma unroll
    for (int kc = 0; kc < 4; ++kc) {
        kf0[kc] = *(const bh8*)(kp0 + 16 * kc);
        kf1[kc] = *(const bh8*)(kp1 + 16 * kc);
    }
    vv0 = *(const bh8*)vp0; vv1 = *(const bh8*)vp1;
    kp0 += (size_t)64 * 1024; kp1 += (size_t)64 * 1024;
    vp0 += (size_t)64 * 1024; vp1 += (size_t)64 * 1024;
#pragma unroll
    for (int j = 0; j < 8; ++j) {
        int d = vd0 + j;
        int swz = ((d & 7) ^ (d >> 3)) << 3;
        Vt[0][(d * 64 + vr) ^ swz]      = ((const __hip_bfloat16*)&vv0)[j];
        Vt[0][(d * 64 + vr + 32) ^ swz] = ((const __hip_bfloat16*)&vv1)[j];
    }
    __syncthreads();

    f32x16 o0 = {0.f}, o1 = {0.f};
    float m_run = -1e30f, l_run = 0.f;
    int cur = 0;

    for (int t = 0; t < 32; ++t) {
        // QK^T: S^T tiles D[i=kv][j=q]
        f32x16 s0 = {0.f}, s1 = {0.f};
#pragma unroll
        for (int kc = 0; kc < 4; ++kc) {
            s0 = __builtin_amdgcn_mfma_f32_32x32x16_bf16(kf0[kc], qf[kc], s0, 0, 0, 0);
            s1 = __builtin_amdgcn_mfma_f32_32x32x16_bf16(kf1[kc], qf[kc], s1, 0, 0, 0);
        }
        // prefetch tile t+1 (hidden under softmax+PV)
        if (t < 31) {
#pragma unroll
            for (int kc = 0; kc < 4; ++kc) {
                kf0[kc] = *(const bh8*)(kp0 + 16 * kc);
                kf1[kc] = *(const bh8*)(kp1 + 16 * kc);
            }
            vv0 = *(const bh8*)vp0; vv1 = *(const bh8*)vp1;
            kp0 += (size_t)64 * 1024; kp1 += (size_t)64 * 1024;
            vp0 += (size_t)64 * 1024; vp1 += (size_t)64 * 1024;
        }

        // scale (log2 domain) + mask bias + row max (lane pair c, c^32 share q=c)
        float mx = -1e30f;
#pragma unroll
        for (int ct = 0; ct < 2; ++ct) {
#pragma unroll
            for (int rb = 0; rb < 4; ++rb) {
                f32x4 bb = *(const f32x4*)&biasS[t * 64 + ct * 32 + rb * 8 + 4 * G];
#pragma unroll
                for (int j = 0; j < 4; ++j) {
                    float sv = (ct ? s1[rb * 4 + j] : s0[rb * 4 + j]) * CSC + bb[j];
                    if (ct) s1[rb * 4 + j] = sv; else s0[rb * 4 + j] = sv;
                    mx = fmaxf(mx, sv);
                }
            }
        }
        mx = fmaxf(mx, __shfl_xor(mx, 32));

        if (__all(mx - m_run <= THRL)) {
            // defer-max: no rescale, P bounded by 2^THRL
            float ls = 0.f;
#pragma unroll
            for (int i = 0; i < 16; ++i) {
                float p0 = __builtin_amdgcn_exp2f(s0[i] - m_run);
                float p1 = __builtin_amdgcn_exp2f(s1[i] - m_run);
                s0[i] = p0; s1[i] = p1; ls += p0 + p1;
            }
            ls += __shfl_xor(ls, 32);
            l_run += ls;
        } else {
            const float m_new = fmaxf(m_run, mx);
            const float fac = __builtin_amdgcn_exp2f(m_run - m_new);
            float ls = 0.f;
#pragma unroll
            for (int i = 0; i < 16; ++i) {
                float p0 = __builtin_amdgcn_exp2f(s0[i] - m_new);
                float p1 = __builtin_amdgcn_exp2f(s1[i] - m_new);
                s0[i] = p0; s1[i] = p1; ls += p0 + p1;
            }
            ls += __shfl_xor(ls, 32);
            l_run = l_run * fac + ls;
            m_run = m_new;
#pragma unroll
            for (int i = 0; i < 16; ++i) { o0[i] *= fac; o1[i] *= fac; }
        }

        // PV: O^T += mfma(V^T-frag, P^T-frag). P^T frag built in-register.
#pragma unroll
        for (int kc2 = 0; kc2 < 4; ++kc2) {
            const f32x16& ps = (kc2 < 2) ? s0 : s1;
            const int R0 = 8 * (kc2 & 1);
            unsigned a0, a1, b0, b1;
            asm("v_cvt_pk_bf16_f32 %0, %1, %2" : "=v"(a0) : "v"(ps[R0 + 0]), "v"(ps[R0 + 1]));
            asm("v_cvt_pk_bf16_f32 %0, %1, %2" : "=v"(a1) : "v"(ps[R0 + 2]), "v"(ps[R0 + 3]));
            asm("v_cvt_pk_bf16_f32 %0, %1, %2" : "=v"(b0) : "v"(ps[R0 + 4]), "v"(ps[R0 + 5]));
            asm("v_cvt_pk_bf16_f32 %0, %1, %2" : "=v"(b1) : "v"(ps[R0 + 6]), "v"(ps[R0 + 7]));
            asm("v_permlane32_swap_b32 %0, %1" : "+v"(a0), "+v"(b0));
            asm("v_permlane32_swap_b32 %0, %1" : "+v"(a1), "+v"(b1));
            uint4v pu = {a0, a1, b0, b1};
            bh8 pf = __builtin_bit_cast(bh8, pu);
            const int kv0 = 16 * kc2 + 8 * G;
            int d0 = c, d1 = c + 32;
            int e0 = (d0 * 64 + kv0) ^ (((d0 & 7) ^ (d0 >> 3)) << 3);
            int e1 = (d1 * 64 + kv0) ^ (((d1 & 7) ^ (d1 >> 3)) << 3);
            bh8 vf0 = *(const bh8*)(&Vt[cur][0] + e0);
            bh8 vf1 = *(const bh8*)(&Vt[cur][0] + e1);
            o0 = __builtin_amdgcn_mfma_f32_32x32x16_bf16(vf0, pf, o0, 0, 0, 0);
            o1 = __builtin_amdgcn_mfma_f32_32x32x16_bf16(vf1, pf, o1, 0, 0, 0);
        }

        // stage V[t+1] into the other buffer
        if (t < 31) {
            __syncthreads();   // all waves done reading Vt[cur^1] (iter t-1)
#pragma unroll
            for (int j = 0; j < 8; ++j) {
                int d = vd0 + j;
                int swz = ((d & 7) ^ (d >> 3)) << 3;
                Vt[cur ^ 1][(d * 64 + vr) ^ swz]      = ((const __hip_bfloat16*)&vv0)[j];
                Vt[cur ^ 1][(d * 64 + vr + 32) ^ swz] = ((const __hip_bfloat16*)&vv1)[j];
            }
            __syncthreads();   // staged
            cur ^= 1;
        }
    }

    // epilogue: O = acc/l (l==0 -> 0), write [B*S, E] bf16, packed stores
    float inv = (l_run > 0.f) ? 1.f / l_run : 0.f;
    __hip_bfloat16* op = Om + (size_t)(b * 2048 + q0 + c) * 1024 + h * 64 + 4 * G;
#pragma unroll
    for (int dt = 0; dt < 2; ++dt) {
#pragma unroll
        for (int rb = 0; rb < 4; ++rb) {
            union { ushort4 u; __hip_bfloat16 hv[4]; } cv;
#pragma unroll
            for (int j = 0; j < 4; ++j) {
                float x = (dt ? o1[rb * 4 + j] : o0[rb * 4 + j]) * inv;
                cv.hv[j] = __float2bfloat16(x);
            }
            *(ushort4*)(op + dt * 32 + rb * 8) = cv.u;
        }
    }
}

// ---------------------------------------------------------------------------
extern "C" void kernel_launch(void* const* d_in, const int* in_sizes, int n_in,
                              void* d_out, int out_size, void* d_ws, size_t ws_size,
                              hipStream_t stream) {
    const float* q  = (const float*)d_in[0];
    const float* k  = (const float*)d_in[1];
    const float* v  = (const float*)d_in[2];
    const int*   mk = (const int*)d_in[3];
    const float* Wq = (const float*)d_in[4];
    const float* bq = (const float*)d_in[5];
    const float* Wk = (const float*)d_in[6];
    const float* bk = (const float*)d_in[7];
    const float* Wv = (const float*)d_in[8];
    const float* bv = (const float*)d_in[9];
    const float* Wo = (const float*)d_in[10];
    const float* bo = (const float*)d_in[11];
    float* out = (float*)d_out;

    const size_t MN = (size_t)8192 * 1024;
    __hip_bfloat16* B0 = (__hip_bfloat16*)d_ws;  // q_bf, later Kw
    __hip_bfloat16* B1 = B0 + MN;                // k_bf, later Vw
    __hip_bfloat16* B2 = B1 + MN;                // v_bf, later Ow
    __hip_bfloat16* B3 = B2 + MN;                // Qw

    cvt3<<<4096, 256, 0, stream>>>(q, k, v, B0, B1, B2);
    gemm_bt<__hip_bfloat16><<<512, 256, 0, stream>>>(B0, Wq, bq, B3, 8192, 1024, 1024); // Qw=B3
    gemm_bt<__hip_bfloat16><<<512, 256, 0, stream>>>(B1, Wk, bk, B0, 8192, 1024, 1024); // Kw=B0
    gemm_bt<__hip_bfloat16><<<512, 256, 0, stream>>>(B2, Wv, bv, B1, 8192, 1024, 1024); // Vw=B1
    attn_kernel<<<1024, 256, 0, stream>>>(B3, B0, B1, mk, B2);                          // Ow=B2
    gemm_bt<float><<<512, 256, 0, stream>>>(B2, Wo, bo, out, 8192, 1024, 1024);
}

// Round 4
// 275.743 us; speedup vs baseline: 1.5315x; 1.5093x over previous
//
#include <hip/hip_runtime.h>
#include <hip/hip_bf16.h>

typedef short bh8 __attribute__((ext_vector_type(8)));      // 8 bf16 (4 VGPR) MFMA frag
typedef float f32x4 __attribute__((ext_vector_type(4)));
typedef float f32x16 __attribute__((ext_vector_type(16)));
typedef unsigned int uint4v __attribute__((ext_vector_type(4)));

#define GLOBAL_P(p) ((const __attribute__((address_space(1))) void*)(p))
#define LDS_P(p)    ((__attribute__((address_space(3))) void*)(p))

__device__ inline bh8 pack8(const float4& a, const float4& b) {
    union { bh8 v; __hip_bfloat16 h[8]; } u;
    u.h[0] = __float2bfloat16(a.x); u.h[1] = __float2bfloat16(a.y);
    u.h[2] = __float2bfloat16(a.z); u.h[3] = __float2bfloat16(a.w);
    u.h[4] = __float2bfloat16(b.x); u.h[5] = __float2bfloat16(b.y);
    u.h[6] = __float2bfloat16(b.z); u.h[7] = __float2bfloat16(b.w);
    return u.v;
}

// ---------------------------------------------------------------------------
// cvt3: f32 -> bf16 for q,k,v (equal sizes). 8 elems/thread/tensor.
// ---------------------------------------------------------------------------
__global__ __launch_bounds__(256) void cvt3(
    const float* __restrict__ a, const float* __restrict__ b, const float* __restrict__ c,
    __hip_bfloat16* __restrict__ oa, __hip_bfloat16* __restrict__ ob, __hip_bfloat16* __restrict__ oc)
{
    size_t i = ((size_t)blockIdx.x * 256 + threadIdx.x) * 8;
    float4 x0 = *(const float4*)(a + i), x1 = *(const float4*)(a + i + 4);
    *(bh8*)(oa + i) = pack8(x0, x1);
    float4 y0 = *(const float4*)(b + i), y1 = *(const float4*)(b + i + 4);
    *(bh8*)(ob + i) = pack8(y0, y1);
    float4 z0 = *(const float4*)(c + i), z1 = *(const float4*)(c + i + 4);
    *(bh8*)(oc + i) = pack8(z0, z1);
}

// cvtW: 4 weight matrices f32 -> bf16 into one contiguous ws region.
__global__ __launch_bounds__(256) void cvtW(
    const float* __restrict__ a, const float* __restrict__ b,
    const float* __restrict__ c, const float* __restrict__ d,
    __hip_bfloat16* __restrict__ o)
{
    int seg = blockIdx.x >> 9;                       // 512 blocks per 1M-elem segment
    const float* src = (seg == 0) ? a : (seg == 1) ? b : (seg == 2) ? c : d;
    size_t i = ((size_t)(blockIdx.x & 511) * 256 + threadIdx.x) * 8;
    float4 x0 = *(const float4*)(src + i), x1 = *(const float4*)(src + i + 4);
    *(bh8*)(o + (size_t)seg * 1048576 + i) = pack8(x0, x1);
}

// ---------------------------------------------------------------------------
// GEMM: C[M,N] = A[M,K] @ W[N,K]^T + bias (torch Linear). A,W bf16, bias f32,
// C f32 or bf16. 128x128 tile, BK=64, 4 waves, mfma_f32_16x16x32_bf16,
// both operands staged via global_load_lds width=16 (m97 structure).
// ---------------------------------------------------------------------------
template <typename TC>
__global__ __launch_bounds__(256) void gemm_bt(
    const __hip_bfloat16* __restrict__ A, const __hip_bfloat16* __restrict__ W,
    const float* __restrict__ bias, TC* __restrict__ C,
    int M, int N, int Ksz)
{
    __shared__ __hip_bfloat16 As[128 * 64];
    __shared__ __hip_bfloat16 Bs[128 * 64];
    const int tid = threadIdx.x;
    const int l = tid & 63, w = tid >> 6;
    const int g4 = l >> 4, rl = l & 15;
    const int nb = N >> 7;
    const int bm = blockIdx.x / nb, bn = blockIdx.x % nb;
    const long m0 = (long)bm * 128, n0 = (long)bn * 128;

    const __hip_bfloat16* ag[4];
    const __hip_bfloat16* wg[4];
    int ldsbase[4];
#pragma unroll
    for (int i = 0; i < 4; ++i) {
        int c = i * 256 + tid;           // chunk 0..1023
        int row = c >> 3, c8 = c & 7;
        ag[i] = A + (m0 + row) * Ksz + c8 * 8;
        wg[i] = W + (n0 + row) * Ksz + c8 * 8;
        ldsbase[i] = (i * 256 + w * 64) * 8;  // wave-uniform glds base (elements)
    }

    const int wr = w >> 1, wc = w & 1;
    f32x4 acc[4][4];
#pragma unroll
    for (int i = 0; i < 4; ++i)
#pragma unroll
        for (int j = 0; j < 4; ++j) acc[i][j] = f32x4{0.f, 0.f, 0.f, 0.f};

    const int nk = Ksz >> 6;
    for (int t = 0; t < nk; ++t) {
        __syncthreads();   // previous tile's LDS reads complete
#pragma unroll
        for (int i = 0; i < 4; ++i) {
            __builtin_amdgcn_global_load_lds(GLOBAL_P(ag[i]), LDS_P((__hip_bfloat16*)As + ldsbase[i]), 16, 0, 0);
            __builtin_amdgcn_global_load_lds(GLOBAL_P(wg[i]), LDS_P((__hip_bfloat16*)Bs + ldsbase[i]), 16, 0, 0);
            ag[i] += 64; wg[i] += 64;
        }
        __syncthreads();   // staged (barrier drains vmcnt)
#pragma unroll
        for (int kc = 0; kc < 2; ++kc) {
            bh8 af[4], bf[4];
#pragma unroll
            for (int mt = 0; mt < 4; ++mt) {
                int row = wr * 64 + mt * 16 + rl;
                af[mt] = *(const bh8*)(As + row * 64 + 8 * g4 + 32 * kc);
            }
#pragma unroll
            for (int nt = 0; nt < 4; ++nt) {
                int row = wc * 64 + nt * 16 + rl;
                bf[nt] = *(const bh8*)(Bs + row * 64 + 8 * g4 + 32 * kc);
            }
#pragma unroll
            for (int mt = 0; mt < 4; ++mt)
#pragma unroll
                for (int nt = 0; nt < 4; ++nt)
                    acc[mt][nt] = __builtin_amdgcn_mfma_f32_16x16x32_bf16(af[mt], bf[nt], acc[mt][nt], 0, 0, 0);
        }
    }

    // epilogue: + bias (f32). C/D: col=lane&15, row=(lane>>4)*4+reg
    float bv[4];
#pragma unroll
    for (int nt = 0; nt < 4; ++nt)
        bv[nt] = bias[n0 + wc * 64 + nt * 16 + rl];
#pragma unroll
    for (int mt = 0; mt < 4; ++mt) {
#pragma unroll
        for (int r = 0; r < 4; ++r) {
            long row = m0 + wr * 64 + mt * 16 + g4 * 4 + r;
            TC* cp = C + row * N + n0 + wc * 64 + rl;
#pragma unroll
            for (int nt = 0; nt < 4; ++nt) {
                float x = acc[mt][nt][r] + bv[nt];
                if constexpr (__is_same(TC, float)) cp[nt * 16] = x;
                else cp[nt * 16] = __float2bfloat16(x);
            }
        }
    }
}

// ---------------------------------------------------------------------------
// Flash attention, B=4 H=16 S=2048 D=64, inputs [B*S, E] bf16 (from ws).
// 4 waves x 32 q-rows (QB=128), KVBLK=64, mfma_f32_32x32x16_bf16, grid 1024.
// Swapped QK^T (lane owns q-row -> in-register softmax, log2 domain).
// Software pipeline pinned with sched_barrier(0): prefetch K(t+1)/V(t+2)
// issued after QK^T(t), cannot sink below softmax. ONE barrier per iter
// (double-buffered V^T tile, write-side 2-way swizzle). Defer-max (T13),
// setprio around MFMA (T5), XCD-swizzled blockIdx (one (b,h) per XCD).
// ---------------------------------------------------------------------------
#define CSC 0.18033688011112042f   /* 0.125 * log2(e) */
#define THRL 11.0f                 /* defer-max threshold, log2 units */

__global__ __launch_bounds__(256, 2) void attn_kernel(
    const __hip_bfloat16* __restrict__ Qm, const __hip_bfloat16* __restrict__ Km,
    const __hip_bfloat16* __restrict__ Vm, const int* __restrict__ mask,
    __hip_bfloat16* __restrict__ Om)
{
    __shared__ __hip_bfloat16 Vt[2][64 * 64];   // V^T double buffer, swizzled
    __shared__ float biasS[2048];               // mask bias for this batch
    const int tid = threadIdx.x;
    const int w = tid >> 6, l = tid & 63;
    const int G = l >> 5, c = l & 31;
    // XCD swizzle: xcd = id&7 owns bh = xcd*8 + (slot>>4); qb = slot&15
    const int id = blockIdx.x;
    const int xcd = id & 7, slot = id >> 3;
    const int bh = xcd * 8 + (slot >> 4);
    const int qb = slot & 15;
    const int b = bh >> 4, h = bh & 15;
    const int q0 = qb * 128 + w * 32;

#pragma unroll
    for (int i = 0; i < 8; ++i) {
        int idx = i * 256 + tid;
        biasS[idx] = (mask[b * 2048 + idx] != 0) ? 0.f : -1e30f;
    }

    // Q B-frags: col j = q = c, k = 8G+jj (+16*kc)
    const __hip_bfloat16* qp = Qm + (size_t)(b * 2048 + q0 + c) * 1024 + h * 64 + 8 * G;
    bh8 qf[4];
#pragma unroll
    for (int kc = 0; kc < 4; ++kc) qf[kc] = *(const bh8*)(qp + 16 * kc);

    const __hip_bfloat16* kbase = Km + (size_t)(b * 2048 + c) * 1024 + h * 64 + 8 * G;
    const int vr = tid >> 3, vd0 = (tid & 7) * 8;
    const __hip_bfloat16* vbase = Vm + (size_t)(b * 2048 + vr) * 1024 + h * 64 + vd0;

    // prologue: K(0) frags; V(0) load+stage into buf 0; V(1) prefetch
    bh8 kf0[4], kf1[4], vv0, vv1;
#pragma unroll
    for (int kc = 0; kc < 4; ++kc) {
        kf0[kc] = *(const bh8*)(kbase + 16 * kc);
        kf1[kc] = *(const bh8*)(kbase + (size_t)32 * 1024 + 16 * kc);
    }
    {
        bh8 a0 = *(const bh8*)vbase;
        bh8 a1 = *(const bh8*)(vbase + (size_t)32 * 1024);
#pragma unroll
        for (int j = 0; j < 8; ++j) {
            int d = vd0 + j;
            int swz = ((d & 7) ^ (d >> 3)) << 3;
            Vt[0][(d * 64 + vr) ^ swz]      = ((const __hip_bfloat16*)&a0)[j];
            Vt[0][(d * 64 + vr + 32) ^ swz] = ((const __hip_bfloat16*)&a1)[j];
        }
    }
    vv0 = *(const bh8*)(vbase + (size_t)64 * 1024);
    vv1 = *(const bh8*)(vbase + (size_t)96 * 1024);

    f32x16 o0 = {0.f}, o1 = {0.f};
    float m_run = -1e30f, l_run = 0.f;

    for (int t = 0; t < 32; ++t) {
        __syncthreads();   // separates iter t-1 LDS reads/writes; drains prefetch
        // stage V(t+1) into buf[(t+1)&1] (vv loaded during iter t-1 / prologue)
        if (t < 31) {
            __hip_bfloat16* dst = &Vt[(t + 1) & 1][0];
#pragma unroll
            for (int j = 0; j < 8; ++j) {
                int d = vd0 + j;
                int swz = ((d & 7) ^ (d >> 3)) << 3;
                dst[(d * 64 + vr) ^ swz]      = ((const __hip_bfloat16*)&vv0)[j];
                dst[(d * 64 + vr + 32) ^ swz] = ((const __hip_bfloat16*)&vv1)[j];
            }
        }

        // QK^T: S^T tiles D[i=kv][j=q]
        f32x16 s0 = {0.f}, s1 = {0.f};
        __builtin_amdgcn_s_setprio(1);
#pragma unroll
        for (int kc = 0; kc < 4; ++kc) {
            s0 = __builtin_amdgcn_mfma_f32_32x32x16_bf16(kf0[kc], qf[kc], s0, 0, 0, 0);
            s1 = __builtin_amdgcn_mfma_f32_32x32x16_bf16(kf1[kc], qf[kc], s1, 0, 0, 0);
        }
        __builtin_amdgcn_s_setprio(0);

        // prefetch K(t+1), V(t+2) — pinned above softmax by sched_barrier
        {
            int tk = (t + 1 < 32) ? t + 1 : 31;
            const __hip_bfloat16* kp = kbase + (size_t)tk * 64 * 1024;
#pragma unroll
            for (int kc = 0; kc < 4; ++kc) {
                kf0[kc] = *(const bh8*)(kp + 16 * kc);
                kf1[kc] = *(const bh8*)(kp + (size_t)32 * 1024 + 16 * kc);
            }
            int tv = (t + 2 < 32) ? t + 2 : 31;
            const __hip_bfloat16* vp = vbase + (size_t)tv * 64 * 1024;
            vv0 = *(const bh8*)vp;
            vv1 = *(const bh8*)(vp + (size_t)32 * 1024);
        }
        __builtin_amdgcn_sched_barrier(0);

        // scale (log2 domain) + mask bias + row max (lane pair c, c^32 share q=c)
        float mx = -1e30f;
#pragma unroll
        for (int ct = 0; ct < 2; ++ct) {
#pragma unroll
            for (int rb = 0; rb < 4; ++rb) {
                f32x4 bb = *(const f32x4*)&biasS[t * 64 + ct * 32 + rb * 8 + 4 * G];
#pragma unroll
                for (int j = 0; j < 4; ++j) {
                    float sv = (ct ? s1[rb * 4 + j] : s0[rb * 4 + j]) * CSC + bb[j];
                    if (ct) s1[rb * 4 + j] = sv; else s0[rb * 4 + j] = sv;
                    mx = fmaxf(mx, sv);
                }
            }
        }
        mx = fmaxf(mx, __shfl_xor(mx, 32));

        if (__all(mx - m_run <= THRL)) {
            // defer-max: no rescale, P bounded by 2^THRL
            float ls = 0.f;
#pragma unroll
            for (int i = 0; i < 16; ++i) {
                float p0 = __builtin_amdgcn_exp2f(s0[i] - m_run);
                float p1 = __builtin_amdgcn_exp2f(s1[i] - m_run);
                s0[i] = p0; s1[i] = p1; ls += p0 + p1;
            }
            ls += __shfl_xor(ls, 32);
            l_run += ls;
        } else {
            const float m_new = fmaxf(m_run, mx);
            const float fac = __builtin_amdgcn_exp2f(m_run - m_new);
            float ls = 0.f;
#pragma unroll
            for (int i = 0; i < 16; ++i) {
                float p0 = __builtin_amdgcn_exp2f(s0[i] - m_new);
                float p1 = __builtin_amdgcn_exp2f(s1[i] - m_new);
                s0[i] = p0; s1[i] = p1; ls += p0 + p1;
            }
            ls += __shfl_xor(ls, 32);
            l_run = l_run * fac + ls;
            m_run = m_new;
#pragma unroll
            for (int i = 0; i < 16; ++i) { o0[i] *= fac; o1[i] *= fac; }
        }

        // PV: O^T += mfma(V^T-frag, P^T-frag). P^T frag built in-register.
        const __hip_bfloat16* vbuf = &Vt[t & 1][0];
#pragma unroll
        for (int kc2 = 0; kc2 < 4; ++kc2) {
            const f32x16& ps = (kc2 < 2) ? s0 : s1;
            const int R0 = 8 * (kc2 & 1);
            unsigned a0, a1, b0, b1;
            asm("v_cvt_pk_bf16_f32 %0, %1, %2" : "=v"(a0) : "v"(ps[R0 + 0]), "v"(ps[R0 + 1]));
            asm("v_cvt_pk_bf16_f32 %0, %1, %2" : "=v"(a1) : "v"(ps[R0 + 2]), "v"(ps[R0 + 3]));
            asm("v_cvt_pk_bf16_f32 %0, %1, %2" : "=v"(b0) : "v"(ps[R0 + 4]), "v"(ps[R0 + 5]));
            asm("v_cvt_pk_bf16_f32 %0, %1, %2" : "=v"(b1) : "v"(ps[R0 + 6]), "v"(ps[R0 + 7]));
            asm("v_permlane32_swap_b32 %0, %1" : "+v"(a0), "+v"(b0));
            asm("v_permlane32_swap_b32 %0, %1" : "+v"(a1), "+v"(b1));
            uint4v pu = {a0, a1, b0, b1};
            bh8 pf = __builtin_bit_cast(bh8, pu);
            const int kv0 = 16 * kc2 + 8 * G;
            int d0 = c, d1 = c + 32;
            int e0 = (d0 * 64 + kv0) ^ (((d0 & 7) ^ (d0 >> 3)) << 3);
            int e1 = (d1 * 64 + kv0) ^ (((d1 & 7) ^ (d1 >> 3)) << 3);
            bh8 vf0 = *(const bh8*)(vbuf + e0);
            bh8 vf1 = *(const bh8*)(vbuf + e1);
            __builtin_amdgcn_s_setprio(1);
            o0 = __builtin_amdgcn_mfma_f32_32x32x16_bf16(vf0, pf, o0, 0, 0, 0);
            o1 = __builtin_amdgcn_mfma_f32_32x32x16_bf16(vf1, pf, o1, 0, 0, 0);
            __builtin_amdgcn_s_setprio(0);
        }
    }

    // epilogue: O = acc/l (l==0 -> 0), write [B*S, E] bf16, packed stores
    float inv = (l_run > 0.f) ? 1.f / l_run : 0.f;
    __hip_bfloat16* op = Om + (size_t)(b * 2048 + q0 + c) * 1024 + h * 64 + 4 * G;
#pragma unroll
    for (int dt = 0; dt < 2; ++dt) {
#pragma unroll
        for (int rb = 0; rb < 4; ++rb) {
            union { ushort4 u; __hip_bfloat16 hv[4]; } cv;
#pragma unroll
            for (int j = 0; j < 4; ++j) {
                float x = (dt ? o1[rb * 4 + j] : o0[rb * 4 + j]) * inv;
                cv.hv[j] = __float2bfloat16(x);
            }
            *(ushort4*)(op + dt * 32 + rb * 8) = cv.u;
        }
    }
}

// ---------------------------------------------------------------------------
extern "C" void kernel_launch(void* const* d_in, const int* in_sizes, int n_in,
                              void* d_out, int out_size, void* d_ws, size_t ws_size,
                              hipStream_t stream) {
    const float* q  = (const float*)d_in[0];
    const float* k  = (const float*)d_in[1];
    const float* v  = (const float*)d_in[2];
    const int*   mk = (const int*)d_in[3];
    const float* Wq = (const float*)d_in[4];
    const float* bq = (const float*)d_in[5];
    const float* Wk = (const float*)d_in[6];
    const float* bk = (const float*)d_in[7];
    const float* Wv = (const float*)d_in[8];
    const float* bv = (const float*)d_in[9];
    const float* Wo = (const float*)d_in[10];
    const float* bo = (const float*)d_in[11];
    float* out = (float*)d_out;

    const size_t MN = (size_t)8192 * 1024;
    const size_t WN = (size_t)1024 * 1024;
    __hip_bfloat16* B0 = (__hip_bfloat16*)d_ws;  // q_bf -> Kw
    __hip_bfloat16* B1 = B0 + MN;                // k_bf -> Vw
    __hip_bfloat16* B2 = B1 + MN;                // v_bf -> Ow
    __hip_bfloat16* B3 = B2 + MN;                // Qw
    __hip_bfloat16* Wb = B3 + MN;                // Wq,Wk,Wv,Wo bf16 (1M elems each)

    cvt3<<<4096, 256, 0, stream>>>(q, k, v, B0, B1, B2);
    cvtW<<<2048, 256, 0, stream>>>(Wq, Wk, Wv, Wo, Wb);
    gemm_bt<__hip_bfloat16><<<512, 256, 0, stream>>>(B0, Wb,          bq, B3, 8192, 1024, 1024); // Qw=B3
    gemm_bt<__hip_bfloat16><<<512, 256, 0, stream>>>(B1, Wb + WN,     bk, B0, 8192, 1024, 1024); // Kw=B0
    gemm_bt<__hip_bfloat16><<<512, 256, 0, stream>>>(B2, Wb + 2 * WN, bv, B1, 8192, 1024, 1024); // Vw=B1
    attn_kernel<<<1024, 256, 0, stream>>>(B3, B0, B1, mk, B2);                                   // Ow=B2
    gemm_bt<float><<<512, 256, 0, stream>>>(B2, Wb + 3 * WN, bo, out, 8192, 1024, 1024);
}